// Round 8
// baseline (175.851 us; speedup 1.0000x reference)
//
#include <hip/hip_runtime.h>
#include <hip/hip_bf16.h>

// Problem constants (B=8, C=256, H=W=64, OG=4, Cg=64, K=9, C_off=72)
#define BATCH 8
#define CIN   256
#define HH    64
#define WW    64
#define HW    4096
#define OG    4
#define CG    64
#define COFF  72

typedef __attribute__((ext_vector_type(8))) _Float16 half8;
typedef __attribute__((ext_vector_type(4))) float floatx4;

static __device__ __forceinline__ half8 splat8(float f) {
    _Float16 h = (_Float16)f;
    return (half8){h, h, h, h, h, h, h, h};
}

// ws layout:
//   offs  fp32  [B][72][H][W]                       bytes [0, 9437184)
//   wT3   fp16  fragment-order deform weights       bytes [9437184, 9732096)
//   woT3  fp16  fragment-order offset-conv weights  bytes [9732096, 10100736)
//   xh    fp16  [b][y][x][c]  NHWC  (8*4096*256)    bytes [10100736, 26877952)
#define OFFS_ELEMS (BATCH * COFF * HH * WW)      // 2359296
#define WT_ELEMS   (OG * 9 * 4 * 2 * 64 * 8)     // 147456
#define WO3_ELEMS  (8 * 9 * 5 * 64 * 8)          // 184320
#define XH_BYTE_OFF ((size_t)OFFS_ELEMS * 4 + (size_t)WT_ELEMS * 2 + (size_t)WO3_ELEMS * 2)
#define NEED_NHWC (XH_BYTE_OFF + (size_t)BATCH * HW * CIN * 2)   // 26877952

#define PREPW_BLOCKS (((WT_ELEMS + WO3_ELEMS) + 255) / 256)      // 1296

// ---------------------------------------------------------------------------
// Merged prep: blocks [0,512) transpose x NCHW fp32 -> NHWC fp16 (one (b,y)
// row each); blocks [512, 512+1296) emit fragment-order fp16 weights.
// ---------------------------------------------------------------------------
__global__ __launch_bounds__(256) void prep_kernel(
    const float* __restrict__ x, const float* __restrict__ w_def,
    const float* __restrict__ w_off, _Float16* __restrict__ xh,
    _Float16* __restrict__ wT3, _Float16* __restrict__ woT3)
{
    const int t = threadIdx.x;
    if (blockIdx.x >= 512) {
        int i = (blockIdx.x - 512) * 256 + t;
        if (i < WT_ELEMS) {
            int j = i & 7;
            int l = (i >> 3) & 63;
            int rest = i >> 9;        // ((g*9+k)*4+mt)*2+kh
            int kh = rest & 1;
            int mt = (rest >> 1) & 3;
            int gk = rest >> 3;       // g*9+k
            int k = gk % 9, g = gk / 9;
            int o = mt * 16 + (l & 15);
            int c = kh * 32 + (l >> 4) * 8 + j;
            wT3[i] = (_Float16)w_def[((size_t)((g * CG + o) * CG + c)) * 9 + k];
        } else if (i < WT_ELEMS + WO3_ELEMS) {
            int idx = i - WT_ELEMS;
            int j = idx & 7;
            int l = (idx >> 3) & 63;
            int rest = idx >> 9;      // (chunk*9+tap)*5 + mt
            int mt = rest % 5;
            int ct = rest / 5;
            int tap = ct % 9, chunk = ct / 9;
            int o = mt * 16 + (l & 15);
            int c = chunk * 32 + (l >> 4) * 8 + j;
            float v = (o < COFF) ? w_off[((size_t)(o * CIN + c)) * 9 + tap] : 0.f;
            woT3[idx] = (_Float16)v;
        }
        return;
    }

    const int b = blockIdx.x >> 6;
    const int y = blockIdx.x & 63;

    __shared__ short tile[64][258];   // [px][c] bit-pattern of fp16

#pragma unroll
    for (int it = 0; it < 16; ++it) {
        int i  = t + it * 256;        // i < 4096
        int c  = i >> 4;
        int p4 = (i & 15) << 2;
        float4 v = *(const float4*)(x + (((size_t)(b * CIN + c)) << 12) + (y << 6) + p4);
        tile[p4 + 0][c] = __builtin_bit_cast(short, (_Float16)v.x);
        tile[p4 + 1][c] = __builtin_bit_cast(short, (_Float16)v.y);
        tile[p4 + 2][c] = __builtin_bit_cast(short, (_Float16)v.z);
        tile[p4 + 3][c] = __builtin_bit_cast(short, (_Float16)v.w);
    }
    __syncthreads();

    _Float16* dst = xh + (((size_t)(b * HW)) << 8) + ((size_t)(y * WW) << 8);
#pragma unroll
    for (int k = 0; k < 8; ++k) {
        int i  = t + k * 256;         // i < 2048
        int p  = i >> 5;
        int c8 = (i & 31) << 3;
        const unsigned* tp = (const unsigned*)&tile[p][c8];
        uint4 r = make_uint4(tp[0], tp[1], tp[2], tp[3]);
        *(uint4*)(dst + ((size_t)p << 8) + c8) = r;
    }
}

// ---------------------------------------------------------------------------
// Kernel 1 v2 (NHWC fp16): offsets = conv3x3(x) + b_off. Implicit GEMM,
// barrier-free K-loop. (unchanged this round)
// ---------------------------------------------------------------------------
__global__ __launch_bounds__(512) void conv_off_nhwc(
    const _Float16* __restrict__ xh, const _Float16* __restrict__ woT3,
    const float* __restrict__ b_off, float* __restrict__ offs)
{
    const int b  = blockIdx.x >> 5;
    const int h0 = (blockIdx.x & 31) << 1;
    const int t  = threadIdx.x;
    const int wv = t >> 6;
    const int l  = t & 63;
    const int lane16 = l & 15;
    const int quad   = l >> 4;
    const int nh = wv & 1;       // output row within the pair
    const int ks = wv >> 1;      // K-split index 0..3 -> chunks {2ks, 2ks+1}

    // [row 0..3][rec 0..65][slot 0..31][8ch] ; slot swizzled: slot^(rec&7)
    __shared__ _Float16 xs[4][66][256];   // 135168 B

    floatx4 acc[5][4];
#pragma unroll
    for (int mt = 0; mt < 5; ++mt)
#pragma unroll
        for (int nf = 0; nf < 4; ++nf) acc[mt][nf] = (floatx4){0.f, 0.f, 0.f, 0.f};

    // ---- stage the whole 4-row window (rows h0-1 .. h0+2), swizzled ----
#pragma unroll
    for (int i = 0; i < 16; ++i) {
        int f    = (i << 9) + t;          // < 8192
        int r    = f >> 11;               // window row 0..3
        int px   = (f >> 5) & 63;
        int slot = f & 31;
        int yy   = h0 - 1 + r;
        uint4 v = make_uint4(0, 0, 0, 0);
        if ((unsigned)yy < 64u)
            v = *(const uint4*)(xh + (((size_t)(b * HW + (yy << 6) + px)) << 8)
                                   + (slot << 3));
        int rec = px + 1;
        *(uint4*)&xs[r][rec][(slot ^ (rec & 7)) << 3] = v;
    }
    // halo records 0 and 65 of each row -> zero
    if (t < 256) {
        int r = t >> 6, side = (t >> 5) & 1, slot = t & 31;
        int rec = side * 65;
        *(uint4*)&xs[r][rec][(slot ^ (rec & 7)) << 3] = make_uint4(0, 0, 0, 0);
    }
    __syncthreads();

    // ---- barrier-free K loop: 2 chunks x 9 taps, fully unrolled ----
#pragma unroll
    for (int ch2 = 0; ch2 < 2; ++ch2) {
        const int ch = ks * 2 + ch2;
#pragma unroll
        for (int tap = 0; tap < 9; ++tap) {
            const int ky = tap / 3, kx = tap % 3;

            const _Float16* ab = woT3 + (((size_t)((ch * 9 + tap) * 5)) << 9) + (l << 3);
            half8 a0 = *(const half8*)(ab);
            half8 a1 = *(const half8*)(ab + 512);
            half8 a2 = *(const half8*)(ab + 1024);
            half8 a3 = *(const half8*)(ab + 1536);
            half8 a4 = *(const half8*)(ab + 2048);

            half8 bf[4];
#pragma unroll
            for (int nf = 0; nf < 4; ++nf) {
                int rec  = nf * 16 + lane16 + kx;
                int slot = (ch * 4 + quad) ^ (rec & 7);
                bf[nf] = *(const half8*)&xs[nh + ky][rec][slot << 3];
            }

#pragma unroll
            for (int nf = 0; nf < 4; ++nf) {
                acc[0][nf] = __builtin_amdgcn_mfma_f32_16x16x32_f16(a0, bf[nf], acc[0][nf], 0, 0, 0);
                acc[1][nf] = __builtin_amdgcn_mfma_f32_16x16x32_f16(a1, bf[nf], acc[1][nf], 0, 0, 0);
                acc[2][nf] = __builtin_amdgcn_mfma_f32_16x16x32_f16(a2, bf[nf], acc[2][nf], 0, 0, 0);
                acc[3][nf] = __builtin_amdgcn_mfma_f32_16x16x32_f16(a3, bf[nf], acc[3][nf], 0, 0, 0);
                acc[4][nf] = __builtin_amdgcn_mfma_f32_16x16x32_f16(a4, bf[nf], acc[4][nf], 0, 0, 0);
            }
        }
    }

    // ---- 4-way K reduction through LDS (reuse xs), then store ----
    __syncthreads();                       // all xs reads done
    float* red = (float*)&xs[0][0][0];     // 6 slices x 5120 f = 122880 B

    if (ks != 0) {
        float* dst = red + (size_t)(((ks - 1) * 2 + nh) * 5120) + (l << 2);
#pragma unroll
        for (int mt = 0; mt < 5; ++mt)
#pragma unroll
            for (int nf = 0; nf < 4; ++nf)
                *(floatx4*)&dst[(mt * 4 + nf) * 256] = acc[mt][nf];
    }
    __syncthreads();

    if (ks == 0) {
#pragma unroll
        for (int s = 0; s < 3; ++s) {
            const float* src = red + (size_t)((s * 2 + nh) * 5120) + (l << 2);
#pragma unroll
            for (int mt = 0; mt < 5; ++mt)
#pragma unroll
                for (int nf = 0; nf < 4; ++nf)
                    acc[mt][nf] += *(const floatx4*)&src[(mt * 4 + nf) * 256];
        }
        const int y = h0 + nh;
#pragma unroll
        for (int mt = 0; mt < 5; ++mt) {
#pragma unroll
            for (int rg = 0; rg < 4; ++rg) {
                int oc = mt * 16 + quad * 4 + rg;
                if (oc < COFF) {
                    float bias = b_off[oc];
#pragma unroll
                    for (int nf = 0; nf < 4; ++nf)
                        offs[(((size_t)(b * COFF + oc)) << 12) + (y << 6) + nf * 16 + lane16] =
                            acc[mt][nf][rg] + bias;
                }
            }
        }
    }
}

// ---------------------------------------------------------------------------
// Kernel 2 v6 (NHWC fp16): deformable conv, MFMA f16, 2-ROW blocks.
// KEY CHANGE: the gather window LDS is GONE. Each block's gather source is
// only ~48KB of xh (whole xh = 16.8MB, fully L2-resident), so bilinear
// corners are read DIRECTLY from global (the exact math of v4's !inWin
// fallback, now the only path). This removes: 8 staging loads+writes per
// thread, halo/window clamp VALU, the dual gather path, all window bank
// conflicts -- and drops LDS 64KB -> 16KB (wa2 only) => 4 blocks/CU
// (32 waves, was ~10). A-path keeps the proven wa2[2] per-tap double-buffer
// with register prefetch and one barrier per tap.
// ---------------------------------------------------------------------------
__global__ __launch_bounds__(512) void deform_nhwc(
    const _Float16* __restrict__ xh, const float* __restrict__ offs,
    const _Float16* __restrict__ wT3, const float* __restrict__ b_def,
    float* __restrict__ out)
{
    const int hh = blockIdx.x & 31;
    const int bg = blockIdx.x >> 5;
    const int g  = bg & 3;
    const int b  = bg >> 2;
    const int h0 = hh << 1;
    const int t  = threadIdx.x;
    const int wv = t >> 6;
    const int l  = t & 63;
    const int lane16 = l & 15;
    const int quad   = l >> 4;
    const int p  = (wv & 3) * 16 + lane16;
    const int hw = h0 + (wv >> 2);        // this wave's output row

    __shared__ _Float16 wa2[2][4096];     // per-tap A dbuf, 2 x 8192 B only

    floatx4 acc[4];
#pragma unroll
    for (int mt = 0; mt < 4; ++mt) acc[mt] = (floatx4){0.f, 0.f, 0.f, 0.f};

    // ---- stage tap-0 A tile (8KB = 512 uint4, 1 per thread) ----
    {
        const uint4* asrc = (const uint4*)(wT3 + ((size_t)(g * 9) << 12));
        uint4 a0 = asrc[t];
        *(uint4*)&wa2[0][t * 8] = a0;
    }

    // prefetch all 18 offset values for this wave's pixel/row
    float dyv[9], dxv[9];
    {
        const float* ofb = offs + (((size_t)(b * COFF + g * 18)) * HH + hw) * WW + p;
#pragma unroll
        for (int k = 0; k < 9; ++k) {
            dyv[k] = ofb[(size_t)(2 * k) * HW];
            dxv[k] = ofb[(size_t)(2 * k + 1) * HW];
        }
    }

    __syncthreads();

    const _Float16* xg = xh + (((size_t)(b * HW)) << 8) + g * 64;
    const int co = quad * 8;

#pragma unroll
    for (int k = 0; k < 9; ++k) {
        // ---- prefetch next tap's A tile into a register ----
        uint4 pw0;
        if (k < 8) {
            const uint4* asrc = (const uint4*)(wT3 + ((size_t)(g * 9 + k + 1) << 12));
            pw0 = asrc[t];
        }

        // ---- bilinear params ----
        float py = dyv[k] + (float)(hw + (k / 3) - 1);
        float px_ = dxv[k] + (float)(p + (k % 3) - 1);
        float y0f = floorf(py), x0f = floorf(px_);
        float fy = py - y0f, fx = px_ - x0f;
        int y0 = (int)y0f, x0 = (int)x0f;
        float wy0 = ((y0 >= 0) & (y0 < HH)) ? (1.f - fy) : 0.f;
        float wy1 = ((y0 >= -1) & (y0 < HH - 1)) ? fy : 0.f;
        float wx0 = ((x0 >= 0) & (x0 < WW)) ? (1.f - fx) : 0.f;
        float wx1 = ((x0 >= -1) & (x0 < WW - 1)) ? fx : 0.f;
        int yia = min(max(y0, 0), HH - 1), yib = min(max(y0 + 1, 0), HH - 1);
        int xia = min(max(x0, 0), WW - 1), xib = min(max(x0 + 1, 0), WW - 1);

        // ---- direct-global bilinear corners (L2-resident xh) ----
        const _Float16* qa = xg + (((size_t)((yia << 6) + xia)) << 8);
        const _Float16* qb = xg + (((size_t)((yia << 6) + xib)) << 8);
        const _Float16* qc = xg + (((size_t)((yib << 6) + xia)) << 8);
        const _Float16* qd = xg + (((size_t)((yib << 6) + xib)) << 8);

        half8 aL = *(const half8*)(qa + co);  half8 aH = *(const half8*)(qa + co + 32);
        half8 bL = *(const half8*)(qb + co);  half8 bH = *(const half8*)(qb + co + 32);
        half8 cL = *(const half8*)(qc + co);  half8 cH = *(const half8*)(qc + co + 32);
        half8 dL = *(const half8*)(qd + co);  half8 dH = *(const half8*)(qd + co + 32);

        // ---- packed fp16 blend ----
        half8 W00 = splat8(wy0 * wx0), W01 = splat8(wy0 * wx1);
        half8 W10 = splat8(wy1 * wx0), W11 = splat8(wy1 * wx1);
        half8 f0 = aL * W00 + bL * W01 + cL * W10 + dL * W11;
        half8 f1 = aH * W00 + bH * W01 + cH * W10 + dH * W11;

        // ---- A-frags from LDS dbuf + MFMA ----
        const _Float16* wk = &wa2[k & 1][l * 8];
#pragma unroll
        for (int mt = 0; mt < 4; ++mt) {
            half8 a0 = *(const half8*)(wk + (mt * 2 + 0) * 512);
            half8 a1 = *(const half8*)(wk + (mt * 2 + 1) * 512);
            acc[mt] = __builtin_amdgcn_mfma_f32_16x16x32_f16(a0, f0, acc[mt], 0, 0, 0);
            acc[mt] = __builtin_amdgcn_mfma_f32_16x16x32_f16(a1, f1, acc[mt], 0, 0, 0);
        }

        // ---- commit next tap's A tile; single barrier per tap ----
        if (k < 8) {
            *(uint4*)&wa2[(k + 1) & 1][t * 8] = pw0;
            __syncthreads();
        }
    }

#pragma unroll
    for (int mt = 0; mt < 4; ++mt) {
#pragma unroll
        for (int rg = 0; rg < 4; ++rg) {
            int o = mt * 16 + quad * 4 + rg;
            float v = acc[mt][rg] + b_def[g * CG + o];
            out[((size_t)(b * CIN + g * CG + o) * HH + hw) * WW + p] = v;
        }
    }
}

// ===========================================================================
// FALLBACK PATH (ws too small for xh): fp32 correctness-first (not expected
// to be taken -- ws has been >= 26.9MB in all rounds).
// ===========================================================================
__global__ __launch_bounds__(256) void conv_off_fb(
    const float* __restrict__ x, const float* __restrict__ w_off,
    const float* __restrict__ b_off, float* __restrict__ offs)
{
    const int b = blockIdx.x >> 6;
    const int h = blockIdx.x & 63;
    const int t = threadIdx.x;
    const int w = t & 63;
    const int q = t >> 6;

    __shared__ float xsf[3][8][WW + 2];
    __shared__ float wtf[9][8][COFF];

    float acc[18];
#pragma unroll
    for (int j = 0; j < 18; ++j) acc[j] = 0.f;

    for (int c0 = 0; c0 < CIN; c0 += 8) {
        __syncthreads();
        for (int i = t; i < 3 * 8 * (WW + 2); i += 256) {
            int wp = i % (WW + 2);
            int rem = i / (WW + 2);
            int cc = rem % 8;
            int ky = rem / 8;
            int yy = h + ky - 1;
            int xx = wp - 1;
            float v = 0.f;
            if (yy >= 0 && yy < HH && xx >= 0 && xx < WW)
                v = x[(((size_t)b * CIN + c0 + cc) * HH + yy) * WW + xx];
            xsf[ky][cc][wp] = v;
        }
        for (int i = t; i < 9 * 8 * COFF; i += 256) {
            int oc = i % COFF;
            int rem = i / COFF;
            int cc = rem % 8;
            int tap = rem / 8;
            wtf[tap][cc][oc] = w_off[((size_t)oc * CIN + c0 + cc) * 9 + tap];
        }
        __syncthreads();
        for (int tap = 0; tap < 9; ++tap) {
            const int ky = tap / 3, kx = tap % 3;
#pragma unroll
            for (int cc = 0; cc < 8; ++cc) {
                float xv = xsf[ky][cc][w + kx];
#pragma unroll
                for (int j = 0; j < 18; ++j)
                    acc[j] += xv * wtf[tap][cc][q * 18 + j];
            }
        }
    }
#pragma unroll
    for (int j = 0; j < 18; ++j) {
        int oc = q * 18 + j;
        offs[(((size_t)b * COFF + oc) * HH + h) * WW + w] = acc[j] + b_off[oc];
    }
}

__global__ __launch_bounds__(256) void deform_fb(
    const float* __restrict__ x, const float* __restrict__ offs,
    const float* __restrict__ w_def, const float* __restrict__ b_def,
    float* __restrict__ out)
{
    const int h  = blockIdx.x & 63;
    const int bg = blockIdx.x >> 6;
    const int g  = bg & 3;
    const int b  = bg >> 2;
    const int t  = threadIdx.x;
    const int w  = t & 63;
    const int q  = t >> 6;

    __shared__ float vlds[CG][WW];
    __shared__ float wt2[CG][CG];
    __shared__ int   sidx[4][WW];
    __shared__ float swgt[4][WW];

    float acc[16];
#pragma unroll
    for (int j = 0; j < 16; ++j) acc[j] = 0.f;

    const float* xg = x + ((size_t)(b * CIN + g * CG)) * HW;

    for (int k = 0; k < 9; ++k) {
        __syncthreads();
        if (t < 64) {
            const int ky = k / 3 - 1, kx = k % 3 - 1;
            size_t obase = (((size_t)b * COFF + g * 18 + k * 2) * HH + h) * WW + w;
            float dy = offs[obase];
            float dx = offs[obase + (size_t)HW];
            float py = dy + (float)(h + ky);
            float px = dx + (float)(w + kx);
            float y0 = floorf(py), x0 = floorf(px);
            float fy = py - y0, fx = px - x0;
#pragma unroll
            for (int cn = 0; cn < 4; ++cn) {
                float yy = y0 + (float)(cn >> 1);
                float xx = x0 + (float)(cn & 1);
                float wy = (cn >> 1) ? fy : (1.f - fy);
                float wx = (cn & 1) ? fx : (1.f - fx);
                bool valid = (yy >= 0.f) && (yy < (float)HH) &&
                             (xx >= 0.f) && (xx < (float)WW);
                int yi = (int)fminf(fmaxf(yy, 0.f), (float)(HH - 1));
                int xi = (int)fminf(fmaxf(xx, 0.f), (float)(WW - 1));
                sidx[cn][w] = yi * WW + xi;
                swgt[cn][w] = valid ? (wy * wx) : 0.f;
            }
        }
        for (int i = t; i < CG * CG; i += 256) {
            int o = i >> 6, c = i & 63;
            wt2[c][o] = w_def[((size_t)(g * CG + o) * CG + c) * 9 + k];
        }
        __syncthreads();

        int   i0 = sidx[0][w], i1 = sidx[1][w], i2 = sidx[2][w], i3 = sidx[3][w];
        float g0 = swgt[0][w], g1 = swgt[1][w], g2 = swgt[2][w], g3 = swgt[3][w];
#pragma unroll
        for (int j = 0; j < 16; ++j) {
            int c = q * 16 + j;
            const float* xc = xg + (size_t)c * HW;
            float v = g0 * xc[i0] + g1 * xc[i1] + g2 * xc[i2] + g3 * xc[i3];
            vlds[c][w] = v;
        }
        __syncthreads();

#pragma unroll 4
        for (int c = 0; c < CG; ++c) {
            float xv = vlds[c][w];
#pragma unroll
            for (int j = 0; j < 16; ++j)
                acc[j] += xv * wt2[c][q * 16 + j];
        }
    }

#pragma unroll
    for (int j = 0; j < 16; ++j) {
        int o = q * 16 + j;
        out[(((size_t)b * CIN + g * CG + o) * HH + h) * WW + w] =
            acc[j] + b_def[g * CG + o];
    }
}

extern "C" void kernel_launch(void* const* d_in, const int* in_sizes, int n_in,
                              void* d_out, int out_size, void* d_ws, size_t ws_size,
                              hipStream_t stream) {
    const float* x     = (const float*)d_in[0];
    const float* w_off = (const float*)d_in[1];
    const float* b_off = (const float*)d_in[2];
    const float* w_def = (const float*)d_in[3];
    const float* b_def = (const float*)d_in[4];
    float* out = (float*)d_out;

    char* ws = (char*)d_ws;
    float*     offs = (float*)ws;
    _Float16*  wT3  = (_Float16*)(ws + (size_t)OFFS_ELEMS * 4);
    _Float16*  woT3 = (_Float16*)(ws + (size_t)OFFS_ELEMS * 4 + (size_t)WT_ELEMS * 2);
    _Float16*  xh   = (_Float16*)(ws + XH_BYTE_OFF);

    if (ws_size >= NEED_NHWC) {
        prep_kernel<<<512 + PREPW_BLOCKS, 256, 0, stream>>>(x, w_def, w_off, xh, wT3, woT3);
        conv_off_nhwc<<<BATCH * 32, 512, 0, stream>>>(xh, woT3, b_off, offs);
        deform_nhwc<<<BATCH * OG * 32, 512, 0, stream>>>(xh, offs, wT3, b_def, out);
    } else {
        conv_off_fb<<<BATCH * HH, 256, 0, stream>>>(x, w_off, b_off, offs);
        deform_fb<<<BATCH * OG * HH, 256, 0, stream>>>(x, offs, w_def, b_def, out);
    }
}

// Round 9
// 140.290 us; speedup vs baseline: 1.2535x; 1.2535x over previous
//
#include <hip/hip_runtime.h>
#include <hip/hip_bf16.h>

// Problem constants (B=8, C=256, H=W=64, OG=4, Cg=64, K=9, C_off=72)
#define BATCH 8
#define CIN   256
#define HH    64
#define WW    64
#define HW    4096
#define OG    4
#define CG    64
#define COFF  72

typedef __attribute__((ext_vector_type(8))) _Float16 half8;
typedef __attribute__((ext_vector_type(4))) float floatx4;

static __device__ __forceinline__ half8 splat8(float f) {
    _Float16 h = (_Float16)f;
    return (half8){h, h, h, h, h, h, h, h};
}

// ws layout:
//   offs  fp32  [B][72][H][W]                       bytes [0, 9437184)
//   wT3   fp16  fragment-order deform weights       bytes [9437184, 9732096)
//   woT3  fp16  fragment-order offset-conv weights  bytes [9732096, 10100736)
//   xh    fp16  [b][y][x][c]  NHWC  (8*4096*256)    bytes [10100736, 26877952)
#define OFFS_ELEMS (BATCH * COFF * HH * WW)      // 2359296
#define WT_ELEMS   (OG * 9 * 4 * 2 * 64 * 8)     // 147456
#define WO3_ELEMS  (8 * 9 * 5 * 64 * 8)          // 184320
#define XH_BYTE_OFF ((size_t)OFFS_ELEMS * 4 + (size_t)WT_ELEMS * 2 + (size_t)WO3_ELEMS * 2)
#define NEED_NHWC (XH_BYTE_OFF + (size_t)BATCH * HW * CIN * 2)   // 26877952

#define PREPW_BLOCKS (((WT_ELEMS + WO3_ELEMS) + 255) / 256)      // 1296

// ---------------------------------------------------------------------------
// Merged prep: blocks [0,512) transpose x NCHW fp32 -> NHWC fp16 (one (b,y)
// row each); blocks [512, 512+1296) emit fragment-order fp16 weights.
// ---------------------------------------------------------------------------
__global__ __launch_bounds__(256) void prep_kernel(
    const float* __restrict__ x, const float* __restrict__ w_def,
    const float* __restrict__ w_off, _Float16* __restrict__ xh,
    _Float16* __restrict__ wT3, _Float16* __restrict__ woT3)
{
    const int t = threadIdx.x;
    if (blockIdx.x >= 512) {
        int i = (blockIdx.x - 512) * 256 + t;
        if (i < WT_ELEMS) {
            int j = i & 7;
            int l = (i >> 3) & 63;
            int rest = i >> 9;        // ((g*9+k)*4+mt)*2+kh
            int kh = rest & 1;
            int mt = (rest >> 1) & 3;
            int gk = rest >> 3;       // g*9+k
            int k = gk % 9, g = gk / 9;
            int o = mt * 16 + (l & 15);
            int c = kh * 32 + (l >> 4) * 8 + j;
            wT3[i] = (_Float16)w_def[((size_t)((g * CG + o) * CG + c)) * 9 + k];
        } else if (i < WT_ELEMS + WO3_ELEMS) {
            int idx = i - WT_ELEMS;
            int j = idx & 7;
            int l = (idx >> 3) & 63;
            int rest = idx >> 9;      // (chunk*9+tap)*5 + mt
            int mt = rest % 5;
            int ct = rest / 5;
            int tap = ct % 9, chunk = ct / 9;
            int o = mt * 16 + (l & 15);
            int c = chunk * 32 + (l >> 4) * 8 + j;
            float v = (o < COFF) ? w_off[((size_t)(o * CIN + c)) * 9 + tap] : 0.f;
            woT3[idx] = (_Float16)v;
        }
        return;
    }

    const int b = blockIdx.x >> 6;
    const int y = blockIdx.x & 63;

    __shared__ short tile[64][258];   // [px][c] bit-pattern of fp16

#pragma unroll
    for (int it = 0; it < 16; ++it) {
        int i  = t + it * 256;        // i < 4096
        int c  = i >> 4;
        int p4 = (i & 15) << 2;
        float4 v = *(const float4*)(x + (((size_t)(b * CIN + c)) << 12) + (y << 6) + p4);
        tile[p4 + 0][c] = __builtin_bit_cast(short, (_Float16)v.x);
        tile[p4 + 1][c] = __builtin_bit_cast(short, (_Float16)v.y);
        tile[p4 + 2][c] = __builtin_bit_cast(short, (_Float16)v.z);
        tile[p4 + 3][c] = __builtin_bit_cast(short, (_Float16)v.w);
    }
    __syncthreads();

    _Float16* dst = xh + (((size_t)(b * HW)) << 8) + ((size_t)(y * WW) << 8);
#pragma unroll
    for (int k = 0; k < 8; ++k) {
        int i  = t + k * 256;         // i < 2048
        int p  = i >> 5;
        int c8 = (i & 31) << 3;
        const unsigned* tp = (const unsigned*)&tile[p][c8];
        uint4 r = make_uint4(tp[0], tp[1], tp[2], tp[3]);
        *(uint4*)(dst + ((size_t)p << 8) + c8) = r;
    }
}

// ---------------------------------------------------------------------------
// Kernel 1 v2 (NHWC fp16): offsets = conv3x3(x) + b_off. Implicit GEMM,
// barrier-free K-loop.
// ---------------------------------------------------------------------------
__global__ __launch_bounds__(512) void conv_off_nhwc(
    const _Float16* __restrict__ xh, const _Float16* __restrict__ woT3,
    const float* __restrict__ b_off, float* __restrict__ offs)
{
    const int b  = blockIdx.x >> 5;
    const int h0 = (blockIdx.x & 31) << 1;
    const int t  = threadIdx.x;
    const int wv = t >> 6;
    const int l  = t & 63;
    const int lane16 = l & 15;
    const int quad   = l >> 4;
    const int nh = wv & 1;       // output row within the pair
    const int ks = wv >> 1;      // K-split index 0..3 -> chunks {2ks, 2ks+1}

    // [row 0..3][rec 0..65][slot 0..31][8ch] ; slot swizzled: slot^(rec&7)
    __shared__ _Float16 xs[4][66][256];   // 135168 B

    floatx4 acc[5][4];
#pragma unroll
    for (int mt = 0; mt < 5; ++mt)
#pragma unroll
        for (int nf = 0; nf < 4; ++nf) acc[mt][nf] = (floatx4){0.f, 0.f, 0.f, 0.f};

    // ---- stage the whole 4-row window (rows h0-1 .. h0+2), swizzled ----
#pragma unroll
    for (int i = 0; i < 16; ++i) {
        int f    = (i << 9) + t;          // < 8192
        int r    = f >> 11;               // window row 0..3
        int px   = (f >> 5) & 63;
        int slot = f & 31;
        int yy   = h0 - 1 + r;
        uint4 v = make_uint4(0, 0, 0, 0);
        if ((unsigned)yy < 64u)
            v = *(const uint4*)(xh + (((size_t)(b * HW + (yy << 6) + px)) << 8)
                                   + (slot << 3));
        int rec = px + 1;
        *(uint4*)&xs[r][rec][(slot ^ (rec & 7)) << 3] = v;
    }
    // halo records 0 and 65 of each row -> zero
    if (t < 256) {
        int r = t >> 6, side = (t >> 5) & 1, slot = t & 31;
        int rec = side * 65;
        *(uint4*)&xs[r][rec][(slot ^ (rec & 7)) << 3] = make_uint4(0, 0, 0, 0);
    }
    __syncthreads();

    // ---- barrier-free K loop: 2 chunks x 9 taps, fully unrolled ----
#pragma unroll
    for (int ch2 = 0; ch2 < 2; ++ch2) {
        const int ch = ks * 2 + ch2;
#pragma unroll
        for (int tap = 0; tap < 9; ++tap) {
            const int ky = tap / 3, kx = tap % 3;

            const _Float16* ab = woT3 + (((size_t)((ch * 9 + tap) * 5)) << 9) + (l << 3);
            half8 a0 = *(const half8*)(ab);
            half8 a1 = *(const half8*)(ab + 512);
            half8 a2 = *(const half8*)(ab + 1024);
            half8 a3 = *(const half8*)(ab + 1536);
            half8 a4 = *(const half8*)(ab + 2048);

            half8 bf[4];
#pragma unroll
            for (int nf = 0; nf < 4; ++nf) {
                int rec  = nf * 16 + lane16 + kx;
                int slot = (ch * 4 + quad) ^ (rec & 7);
                bf[nf] = *(const half8*)&xs[nh + ky][rec][slot << 3];
            }

#pragma unroll
            for (int nf = 0; nf < 4; ++nf) {
                acc[0][nf] = __builtin_amdgcn_mfma_f32_16x16x32_f16(a0, bf[nf], acc[0][nf], 0, 0, 0);
                acc[1][nf] = __builtin_amdgcn_mfma_f32_16x16x32_f16(a1, bf[nf], acc[1][nf], 0, 0, 0);
                acc[2][nf] = __builtin_amdgcn_mfma_f32_16x16x32_f16(a2, bf[nf], acc[2][nf], 0, 0, 0);
                acc[3][nf] = __builtin_amdgcn_mfma_f32_16x16x32_f16(a3, bf[nf], acc[3][nf], 0, 0, 0);
                acc[4][nf] = __builtin_amdgcn_mfma_f32_16x16x32_f16(a4, bf[nf], acc[4][nf], 0, 0, 0);
            }
        }
    }

    // ---- 4-way K reduction through LDS (reuse xs), then store ----
    __syncthreads();                       // all xs reads done
    float* red = (float*)&xs[0][0][0];     // 6 slices x 5120 f = 122880 B

    if (ks != 0) {
        float* dst = red + (size_t)(((ks - 1) * 2 + nh) * 5120) + (l << 2);
#pragma unroll
        for (int mt = 0; mt < 5; ++mt)
#pragma unroll
            for (int nf = 0; nf < 4; ++nf)
                *(floatx4*)&dst[(mt * 4 + nf) * 256] = acc[mt][nf];
    }
    __syncthreads();

    if (ks == 0) {
#pragma unroll
        for (int s = 0; s < 3; ++s) {
            const float* src = red + (size_t)((s * 2 + nh) * 5120) + (l << 2);
#pragma unroll
            for (int mt = 0; mt < 5; ++mt)
#pragma unroll
                for (int nf = 0; nf < 4; ++nf)
                    acc[mt][nf] += *(const floatx4*)&src[(mt * 4 + nf) * 256];
        }
        const int y = h0 + nh;
#pragma unroll
        for (int mt = 0; mt < 5; ++mt) {
#pragma unroll
            for (int rg = 0; rg < 4; ++rg) {
                int oc = mt * 16 + quad * 4 + rg;
                if (oc < COFF) {
                    float bias = b_off[oc];
#pragma unroll
                    for (int nf = 0; nf < 4; ++nf)
                        offs[(((size_t)(b * COFF + oc)) << 12) + (y << 6) + nf * 16 + lane16] =
                            acc[mt][nf][rg] + bias;
                }
            }
        }
    }
}

// ---------------------------------------------------------------------------
// Kernel 2 v4 (NHWC fp16): deformable conv, MFMA f16, 2-ROW blocks.
// PROVEN-BEST configuration (round-5 measurement, 141.4us total):
//  * wa2[2] per-tap A double-buffer with register prefetch, ONE barrier/tap.
//  * XOR-swizzled unpadded gather window [r][px][slot^(px&7)] (128B records)
//    -- the LDS window is the coalescing device: v6 (windowless, direct
//    global gather) measured 74.9us because per-lane scatter hits 64
//    cachelines per load instruction (L1 tag-throughput bound).
//  * 48KB window + 16KB wa2 = 64KB => 2 blocks/CU.
// ---------------------------------------------------------------------------
__global__ __launch_bounds__(512) void deform_nhwc(
    const _Float16* __restrict__ xh, const float* __restrict__ offs,
    const _Float16* __restrict__ wT3, const float* __restrict__ b_def,
    float* __restrict__ out)
{
    const int hh = blockIdx.x & 31;
    const int bg = blockIdx.x >> 5;
    const int g  = bg & 3;
    const int b  = bg >> 2;
    const int h0 = hh << 1;
    const int t  = threadIdx.x;
    const int wv = t >> 6;
    const int l  = t & 63;
    const int lane16 = l & 15;
    const int quad   = l >> 4;
    const int p  = (wv & 3) * 16 + lane16;
    const int hw = h0 + (wv >> 2);        // this wave's output row

    // [r 0..5][px 0..63][8 slots of 16B, phys slot = logical ^ (px&7)]
    __shared__ _Float16 ls[6 * 64 * 64];    // 49152 B
    __shared__ _Float16 wa2[2][4096];       // per-tap A dbuf, 2 x 8192 B

    floatx4 acc[4];
#pragma unroll
    for (int mt = 0; mt < 4; ++mt) acc[mt] = (floatx4){0.f, 0.f, 0.f, 0.f};

    // ---- stage 6-row window (rows h0-2..h0+3, group g's 64 channels) ----
#pragma unroll
    for (int it = 0; it < 6; ++it) {
        int id  = it * 512 + t;          // < 3072
        int c16 = id & 7;                // logical slot
        int px  = (id >> 3) & 63;
        int r   = id >> 9;               // 0..5
        int r_img = h0 - 2 + r;
        uint4 v = make_uint4(0, 0, 0, 0);
        if ((unsigned)r_img < 64u)
            v = *(const uint4*)(xh + (((size_t)(b * HW + (r_img << 6) + px)) << 8)
                                   + g * 64 + c16 * 8);
        *(uint4*)&ls[((r * 64 + px) << 6) + ((c16 ^ (px & 7)) << 3)] = v;
    }

    // ---- stage tap-0 A tile (8KB = 512 uint4, 1 per thread) ----
    {
        const uint4* asrc = (const uint4*)(wT3 + ((size_t)(g * 9) << 12));
        uint4 a0 = asrc[t];
        *(uint4*)&wa2[0][t * 8] = a0;
    }

    // prefetch all 18 offset values for this wave's pixel/row
    float dyv[9], dxv[9];
    {
        const float* ofb = offs + (((size_t)(b * COFF + g * 18)) * HH + hw) * WW + p;
#pragma unroll
        for (int k = 0; k < 9; ++k) {
            dyv[k] = ofb[(size_t)(2 * k) * HW];
            dxv[k] = ofb[(size_t)(2 * k + 1) * HW];
        }
    }

    __syncthreads();

    const _Float16* xg = xh + (((size_t)(b * HW)) << 8) + g * 64;

#pragma unroll
    for (int k = 0; k < 9; ++k) {
        // ---- prefetch next tap's A tile into a register ----
        uint4 pw0;
        if (k < 8) {
            const uint4* asrc = (const uint4*)(wT3 + ((size_t)(g * 9 + k + 1) << 12));
            pw0 = asrc[t];
        }

        // ---- bilinear params ----
        float py = dyv[k] + (float)(hw + (k / 3) - 1);
        float px_ = dxv[k] + (float)(p + (k % 3) - 1);
        float y0f = floorf(py), x0f = floorf(px_);
        float fy = py - y0f, fx = px_ - x0f;
        int y0 = (int)y0f, x0 = (int)x0f;
        float wy0 = ((y0 >= 0) & (y0 < HH)) ? (1.f - fy) : 0.f;
        float wy1 = ((y0 >= -1) & (y0 < HH - 1)) ? fy : 0.f;
        float wx0 = ((x0 >= 0) & (x0 < WW)) ? (1.f - fx) : 0.f;
        float wx1 = ((x0 >= -1) & (x0 < WW - 1)) ? fx : 0.f;
        int yia = min(max(y0, 0), HH - 1), yib = min(max(y0 + 1, 0), HH - 1);
        int xia = min(max(x0, 0), WW - 1), xib = min(max(x0 + 1, 0), WW - 1);
        bool inWin = (y0 >= h0 - 2) & (y0 <= h0 + 2);

        int wa_ = min(max(yia - (h0 - 2), 0), 5);
        int wb_ = min(max(yib - (h0 - 2), 0), 5);

        // swizzled gather: phys slot = quad ^ (px&7); high half-frag = ^32
        int soa = (quad ^ (xia & 7)) << 3;
        int sob = (quad ^ (xib & 7)) << 3;
        const _Float16* pa = ls + ((wa_ * 64 + xia) << 6);
        const _Float16* pb = ls + ((wa_ * 64 + xib) << 6);
        const _Float16* pc = ls + ((wb_ * 64 + xia) << 6);
        const _Float16* pd = ls + ((wb_ * 64 + xib) << 6);

        half8 aL = *(const half8*)(pa + soa);
        half8 bL = *(const half8*)(pb + sob);
        half8 cL = *(const half8*)(pc + soa);
        half8 dL = *(const half8*)(pd + sob);
        half8 aH = *(const half8*)(pa + (soa ^ 32));
        half8 bH = *(const half8*)(pb + (sob ^ 32));
        half8 cH = *(const half8*)(pc + (soa ^ 32));
        half8 dH = *(const half8*)(pd + (sob ^ 32));

        if (!inWin) {   // rare: sample escaped the staged window (still exact)
            const int co = quad * 8;
            const _Float16* qa = xg + (((size_t)((yia << 6) + xia)) << 8);
            const _Float16* qb = xg + (((size_t)((yia << 6) + xib)) << 8);
            const _Float16* qc = xg + (((size_t)((yib << 6) + xia)) << 8);
            const _Float16* qd = xg + (((size_t)((yib << 6) + xib)) << 8);
            aL = *(const half8*)(qa + co);  aH = *(const half8*)(qa + co + 32);
            bL = *(const half8*)(qb + co);  bH = *(const half8*)(qb + co + 32);
            cL = *(const half8*)(qc + co);  cH = *(const half8*)(qc + co + 32);
            dL = *(const half8*)(qd + co);  dH = *(const half8*)(qd + co + 32);
        }

        // ---- packed fp16 blend ----
        half8 W00 = splat8(wy0 * wx0), W01 = splat8(wy0 * wx1);
        half8 W10 = splat8(wy1 * wx0), W11 = splat8(wy1 * wx1);
        half8 f0 = aL * W00 + bL * W01 + cL * W10 + dL * W11;
        half8 f1 = aH * W00 + bH * W01 + cH * W10 + dH * W11;

        // ---- A-frags from LDS dbuf + MFMA ----
        const _Float16* wk = &wa2[k & 1][l * 8];
#pragma unroll
        for (int mt = 0; mt < 4; ++mt) {
            half8 a0 = *(const half8*)(wk + (mt * 2 + 0) * 512);
            half8 a1 = *(const half8*)(wk + (mt * 2 + 1) * 512);
            acc[mt] = __builtin_amdgcn_mfma_f32_16x16x32_f16(a0, f0, acc[mt], 0, 0, 0);
            acc[mt] = __builtin_amdgcn_mfma_f32_16x16x32_f16(a1, f1, acc[mt], 0, 0, 0);
        }

        // ---- commit next tap's A tile; single barrier per tap ----
        if (k < 8) {
            *(uint4*)&wa2[(k + 1) & 1][t * 8] = pw0;
            __syncthreads();
        }
    }

#pragma unroll
    for (int mt = 0; mt < 4; ++mt) {
#pragma unroll
        for (int rg = 0; rg < 4; ++rg) {
            int o = mt * 16 + quad * 4 + rg;
            float v = acc[mt][rg] + b_def[g * CG + o];
            out[((size_t)(b * CIN + g * CG + o) * HH + hw) * WW + p] = v;
        }
    }
}

// ===========================================================================
// FALLBACK PATH (ws too small for xh): fp32 correctness-first (not expected
// to be taken -- ws has been >= 26.9MB in all rounds).
// ===========================================================================
__global__ __launch_bounds__(256) void conv_off_fb(
    const float* __restrict__ x, const float* __restrict__ w_off,
    const float* __restrict__ b_off, float* __restrict__ offs)
{
    const int b = blockIdx.x >> 6;
    const int h = blockIdx.x & 63;
    const int t = threadIdx.x;
    const int w = t & 63;
    const int q = t >> 6;

    __shared__ float xsf[3][8][WW + 2];
    __shared__ float wtf[9][8][COFF];

    float acc[18];
#pragma unroll
    for (int j = 0; j < 18; ++j) acc[j] = 0.f;

    for (int c0 = 0; c0 < CIN; c0 += 8) {
        __syncthreads();
        for (int i = t; i < 3 * 8 * (WW + 2); i += 256) {
            int wp = i % (WW + 2);
            int rem = i / (WW + 2);
            int cc = rem % 8;
            int ky = rem / 8;
            int yy = h + ky - 1;
            int xx = wp - 1;
            float v = 0.f;
            if (yy >= 0 && yy < HH && xx >= 0 && xx < WW)
                v = x[(((size_t)b * CIN + c0 + cc) * HH + yy) * WW + xx];
            xsf[ky][cc][wp] = v;
        }
        for (int i = t; i < 9 * 8 * COFF; i += 256) {
            int oc = i % COFF;
            int rem = i / COFF;
            int cc = rem % 8;
            int tap = rem / 8;
            wtf[tap][cc][oc] = w_off[((size_t)oc * CIN + c0 + cc) * 9 + tap];
        }
        __syncthreads();
        for (int tap = 0; tap < 9; ++tap) {
            const int ky = tap / 3, kx = tap % 3;
#pragma unroll
            for (int cc = 0; cc < 8; ++cc) {
                float xv = xsf[ky][cc][w + kx];
#pragma unroll
                for (int j = 0; j < 18; ++j)
                    acc[j] += xv * wtf[tap][cc][q * 18 + j];
            }
        }
    }
#pragma unroll
    for (int j = 0; j < 18; ++j) {
        int oc = q * 18 + j;
        offs[(((size_t)b * COFF + oc) * HH + h) * WW + w] = acc[j] + b_off[oc];
    }
}

__global__ __launch_bounds__(256) void deform_fb(
    const float* __restrict__ x, const float* __restrict__ offs,
    const float* __restrict__ w_def, const float* __restrict__ b_def,
    float* __restrict__ out)
{
    const int h  = blockIdx.x & 63;
    const int bg = blockIdx.x >> 6;
    const int g  = bg & 3;
    const int b  = bg >> 2;
    const int t  = threadIdx.x;
    const int w  = t & 63;
    const int q  = t >> 6;

    __shared__ float vlds[CG][WW];
    __shared__ float wt2[CG][CG];
    __shared__ int   sidx[4][WW];
    __shared__ float swgt[4][WW];

    float acc[16];
#pragma unroll
    for (int j = 0; j < 16; ++j) acc[j] = 0.f;

    const float* xg = x + ((size_t)(b * CIN + g * CG)) * HW;

    for (int k = 0; k < 9; ++k) {
        __syncthreads();
        if (t < 64) {
            const int ky = k / 3 - 1, kx = k % 3 - 1;
            size_t obase = (((size_t)b * COFF + g * 18 + k * 2) * HH + h) * WW + w;
            float dy = offs[obase];
            float dx = offs[obase + (size_t)HW];
            float py = dy + (float)(h + ky);
            float px = dx + (float)(w + kx);
            float y0 = floorf(py), x0 = floorf(px);
            float fy = py - y0, fx = px - x0;
#pragma unroll
            for (int cn = 0; cn < 4; ++cn) {
                float yy = y0 + (float)(cn >> 1);
                float xx = x0 + (float)(cn & 1);
                float wy = (cn >> 1) ? fy : (1.f - fy);
                float wx = (cn & 1) ? fx : (1.f - fx);
                bool valid = (yy >= 0.f) && (yy < (float)HH) &&
                             (xx >= 0.f) && (xx < (float)WW);
                int yi = (int)fminf(fmaxf(yy, 0.f), (float)(HH - 1));
                int xi = (int)fminf(fmaxf(xx, 0.f), (float)(WW - 1));
                sidx[cn][w] = yi * WW + xi;
                swgt[cn][w] = valid ? (wy * wx) : 0.f;
            }
        }
        for (int i = t; i < CG * CG; i += 256) {
            int o = i >> 6, c = i & 63;
            wt2[c][o] = w_def[((size_t)(g * CG + o) * CG + c) * 9 + k];
        }
        __syncthreads();

        int   i0 = sidx[0][w], i1 = sidx[1][w], i2 = sidx[2][w], i3 = sidx[3][w];
        float g0 = swgt[0][w], g1 = swgt[1][w], g2 = swgt[2][w], g3 = swgt[3][w];
#pragma unroll
        for (int j = 0; j < 16; ++j) {
            int c = q * 16 + j;
            const float* xc = xg + (size_t)c * HW;
            float v = g0 * xc[i0] + g1 * xc[i1] + g2 * xc[i2] + g3 * xc[i3];
            vlds[c][w] = v;
        }
        __syncthreads();

#pragma unroll 4
        for (int c = 0; c < CG; ++c) {
            float xv = vlds[c][w];
#pragma unroll
            for (int j = 0; j < 16; ++j)
                acc[j] += xv * wt2[c][q * 16 + j];
        }
    }

#pragma unroll
    for (int j = 0; j < 16; ++j) {
        int o = q * 16 + j;
        out[(((size_t)b * CIN + g * CG + o) * HH + h) * WW + w] =
            acc[j] + b_def[g * CG + o];
    }
}

extern "C" void kernel_launch(void* const* d_in, const int* in_sizes, int n_in,
                              void* d_out, int out_size, void* d_ws, size_t ws_size,
                              hipStream_t stream) {
    const float* x     = (const float*)d_in[0];
    const float* w_off = (const float*)d_in[1];
    const float* b_off = (const float*)d_in[2];
    const float* w_def = (const float*)d_in[3];
    const float* b_def = (const float*)d_in[4];
    float* out = (float*)d_out;

    char* ws = (char*)d_ws;
    float*     offs = (float*)ws;
    _Float16*  wT3  = (_Float16*)(ws + (size_t)OFFS_ELEMS * 4);
    _Float16*  woT3 = (_Float16*)(ws + (size_t)OFFS_ELEMS * 4 + (size_t)WT_ELEMS * 2);
    _Float16*  xh   = (_Float16*)(ws + XH_BYTE_OFF);

    if (ws_size >= NEED_NHWC) {
        prep_kernel<<<512 + PREPW_BLOCKS, 256, 0, stream>>>(x, w_def, w_off, xh, wT3, woT3);
        conv_off_nhwc<<<BATCH * 32, 512, 0, stream>>>(xh, woT3, b_off, offs);
        deform_nhwc<<<BATCH * OG * 32, 512, 0, stream>>>(xh, offs, wT3, b_def, out);
    } else {
        conv_off_fb<<<BATCH * HH, 256, 0, stream>>>(x, w_off, b_off, offs);
        deform_fb<<<BATCH * OG * HH, 256, 0, stream>>>(x, offs, w_def, b_def, out);
    }
}

// Round 10
// 140.197 us; speedup vs baseline: 1.2543x; 1.0007x over previous
//
#include <hip/hip_runtime.h>
#include <hip/hip_bf16.h>

// Problem constants (B=8, C=256, H=W=64, OG=4, Cg=64, K=9, C_off=72)
#define BATCH 8
#define CIN   256
#define HH    64
#define WW    64
#define HW    4096
#define OG    4
#define CG    64
#define COFF  72

typedef __attribute__((ext_vector_type(8))) _Float16 half8;
typedef __attribute__((ext_vector_type(4))) float floatx4;

static __device__ __forceinline__ half8 splat8(float f) {
    _Float16 h = (_Float16)f;
    return (half8){h, h, h, h, h, h, h, h};
}

// ws layout:
//   offs  fp32  [B][72][H][W]                       bytes [0, 9437184)
//   wT3   fp16  fragment-order deform weights       bytes [9437184, 9732096)
//   woT3  fp16  fragment-order offset-conv weights  bytes [9732096, 10100736)
//   xh    fp16  [b][y][x][c]  NHWC  (8*4096*256)    bytes [10100736, 26877952)
#define OFFS_ELEMS (BATCH * COFF * HH * WW)      // 2359296
#define WT_ELEMS   (OG * 9 * 4 * 2 * 64 * 8)     // 147456
#define WO3_ELEMS  (8 * 9 * 5 * 64 * 8)          // 184320
#define XH_BYTE_OFF ((size_t)OFFS_ELEMS * 4 + (size_t)WT_ELEMS * 2 + (size_t)WO3_ELEMS * 2)
#define NEED_NHWC (XH_BYTE_OFF + (size_t)BATCH * HW * CIN * 2)   // 26877952

#define PREPW_BLOCKS (((WT_ELEMS + WO3_ELEMS) + 255) / 256)      // 1296

// ---------------------------------------------------------------------------
// Merged prep: blocks [0,512) transpose x NCHW fp32 -> NHWC fp16 (one (b,y)
// row each); blocks [512, 512+1296) emit fragment-order fp16 weights.
// ---------------------------------------------------------------------------
__global__ __launch_bounds__(256) void prep_kernel(
    const float* __restrict__ x, const float* __restrict__ w_def,
    const float* __restrict__ w_off, _Float16* __restrict__ xh,
    _Float16* __restrict__ wT3, _Float16* __restrict__ woT3)
{
    const int t = threadIdx.x;
    if (blockIdx.x >= 512) {
        int i = (blockIdx.x - 512) * 256 + t;
        if (i < WT_ELEMS) {
            int j = i & 7;
            int l = (i >> 3) & 63;
            int rest = i >> 9;        // ((g*9+k)*4+mt)*2+kh
            int kh = rest & 1;
            int mt = (rest >> 1) & 3;
            int gk = rest >> 3;       // g*9+k
            int k = gk % 9, g = gk / 9;
            int o = mt * 16 + (l & 15);
            int c = kh * 32 + (l >> 4) * 8 + j;
            wT3[i] = (_Float16)w_def[((size_t)((g * CG + o) * CG + c)) * 9 + k];
        } else if (i < WT_ELEMS + WO3_ELEMS) {
            int idx = i - WT_ELEMS;
            int j = idx & 7;
            int l = (idx >> 3) & 63;
            int rest = idx >> 9;      // (chunk*9+tap)*5 + mt
            int mt = rest % 5;
            int ct = rest / 5;
            int tap = ct % 9, chunk = ct / 9;
            int o = mt * 16 + (l & 15);
            int c = chunk * 32 + (l >> 4) * 8 + j;
            float v = (o < COFF) ? w_off[((size_t)(o * CIN + c)) * 9 + tap] : 0.f;
            woT3[idx] = (_Float16)v;
        }
        return;
    }

    const int b = blockIdx.x >> 6;
    const int y = blockIdx.x & 63;

    __shared__ short tile[64][258];   // [px][c] bit-pattern of fp16

#pragma unroll
    for (int it = 0; it < 16; ++it) {
        int i  = t + it * 256;        // i < 4096
        int c  = i >> 4;
        int p4 = (i & 15) << 2;
        float4 v = *(const float4*)(x + (((size_t)(b * CIN + c)) << 12) + (y << 6) + p4);
        tile[p4 + 0][c] = __builtin_bit_cast(short, (_Float16)v.x);
        tile[p4 + 1][c] = __builtin_bit_cast(short, (_Float16)v.y);
        tile[p4 + 2][c] = __builtin_bit_cast(short, (_Float16)v.z);
        tile[p4 + 3][c] = __builtin_bit_cast(short, (_Float16)v.w);
    }
    __syncthreads();

    _Float16* dst = xh + (((size_t)(b * HW)) << 8) + ((size_t)(y * WW) << 8);
#pragma unroll
    for (int k = 0; k < 8; ++k) {
        int i  = t + k * 256;         // i < 2048
        int p  = i >> 5;
        int c8 = (i & 31) << 3;
        const unsigned* tp = (const unsigned*)&tile[p][c8];
        uint4 r = make_uint4(tp[0], tp[1], tp[2], tp[3]);
        *(uint4*)(dst + ((size_t)p << 8) + c8) = r;
    }
}

// ---------------------------------------------------------------------------
// Kernel 1 v3 (NHWC fp16): offsets = conv3x3(x) + b_off. Implicit GEMM,
// barrier-free K-loop. NEW vs v2: explicit 1-deep register ping-pong aw[2][5]
// for the per-kstep A-frag loads -- round-0 profile showed VGPR_Count=52,
// i.e. the compiler serialized each kstep's 5 L2 loads against its MFMAs
// (18 x ~250cy latency chain). LDS caps occupancy at 8 waves/CU so the VGPR
// budget is ~256: spend 40 on a ping-pong so kstep k+1's loads are in
// flight under kstep k's B-reads + 20 MFMAs. Static indices after unroll.
// ---------------------------------------------------------------------------
__global__ __launch_bounds__(512) void conv_off_nhwc(
    const _Float16* __restrict__ xh, const _Float16* __restrict__ woT3,
    const float* __restrict__ b_off, float* __restrict__ offs)
{
    const int b  = blockIdx.x >> 5;
    const int h0 = (blockIdx.x & 31) << 1;
    const int t  = threadIdx.x;
    const int wv = t >> 6;
    const int l  = t & 63;
    const int lane16 = l & 15;
    const int quad   = l >> 4;
    const int nh = wv & 1;       // output row within the pair
    const int ks = wv >> 1;      // K-split index 0..3 -> chunks {2ks, 2ks+1}

    // [row 0..3][rec 0..65][slot 0..31][8ch] ; slot swizzled: slot^(rec&7)
    __shared__ _Float16 xs[4][66][256];   // 135168 B

    floatx4 acc[5][4];
#pragma unroll
    for (int mt = 0; mt < 5; ++mt)
#pragma unroll
        for (int nf = 0; nf < 4; ++nf) acc[mt][nf] = (floatx4){0.f, 0.f, 0.f, 0.f};

    // ---- stage the whole 4-row window (rows h0-1 .. h0+2), swizzled ----
#pragma unroll
    for (int i = 0; i < 16; ++i) {
        int f    = (i << 9) + t;          // < 8192
        int r    = f >> 11;               // window row 0..3
        int px   = (f >> 5) & 63;
        int slot = f & 31;
        int yy   = h0 - 1 + r;
        uint4 v = make_uint4(0, 0, 0, 0);
        if ((unsigned)yy < 64u)
            v = *(const uint4*)(xh + (((size_t)(b * HW + (yy << 6) + px)) << 8)
                                   + (slot << 3));
        int rec = px + 1;
        *(uint4*)&xs[r][rec][(slot ^ (rec & 7)) << 3] = v;
    }
    // halo records 0 and 65 of each row -> zero
    if (t < 256) {
        int r = t >> 6, side = (t >> 5) & 1, slot = t & 31;
        int rec = side * 65;
        *(uint4*)&xs[r][rec][(slot ^ (rec & 7)) << 3] = make_uint4(0, 0, 0, 0);
    }

    // A base for this wave's K-split (flattened kstep kk = ch2*9 + tap)
    const _Float16* abase = woT3 + (l << 3);

    // issue kstep-0 A loads BEFORE the stage barrier so they overlap it
    half8 aw[2][5];
    {
        const _Float16* ab = abase + (((size_t)(((ks * 2) * 9 + 0) * 5)) << 9);
#pragma unroll
        for (int m = 0; m < 5; ++m) aw[0][m] = *(const half8*)(ab + m * 512);
    }

    __syncthreads();

    // ---- barrier-free K loop: 18 flattened ksteps, fully unrolled,
    //      A register ping-pong 1 step ahead ----
#pragma unroll
    for (int kk = 0; kk < 18; ++kk) {
        if (kk < 17) {
            const int nch  = ks * 2 + ((kk + 1) / 9);
            const int ntap = (kk + 1) % 9;
            const _Float16* ab = abase + (((size_t)((nch * 9 + ntap) * 5)) << 9);
#pragma unroll
            for (int m = 0; m < 5; ++m)
                aw[(kk + 1) & 1][m] = *(const half8*)(ab + m * 512);
        }

        const int ch  = ks * 2 + (kk / 9);
        const int tap = kk % 9;
        const int ky = tap / 3, kx = tap % 3;

        half8 bf[4];
#pragma unroll
        for (int nf = 0; nf < 4; ++nf) {
            int rec  = nf * 16 + lane16 + kx;
            int slot = (ch * 4 + quad) ^ (rec & 7);
            bf[nf] = *(const half8*)&xs[nh + ky][rec][slot << 3];
        }

#pragma unroll
        for (int nf = 0; nf < 4; ++nf) {
            acc[0][nf] = __builtin_amdgcn_mfma_f32_16x16x32_f16(aw[kk & 1][0], bf[nf], acc[0][nf], 0, 0, 0);
            acc[1][nf] = __builtin_amdgcn_mfma_f32_16x16x32_f16(aw[kk & 1][1], bf[nf], acc[1][nf], 0, 0, 0);
            acc[2][nf] = __builtin_amdgcn_mfma_f32_16x16x32_f16(aw[kk & 1][2], bf[nf], acc[2][nf], 0, 0, 0);
            acc[3][nf] = __builtin_amdgcn_mfma_f32_16x16x32_f16(aw[kk & 1][3], bf[nf], acc[3][nf], 0, 0, 0);
            acc[4][nf] = __builtin_amdgcn_mfma_f32_16x16x32_f16(aw[kk & 1][4], bf[nf], acc[4][nf], 0, 0, 0);
        }
    }

    // ---- 4-way K reduction through LDS (reuse xs), then store ----
    __syncthreads();                       // all xs reads done
    float* red = (float*)&xs[0][0][0];     // 6 slices x 5120 f = 122880 B

    if (ks != 0) {
        float* dst = red + (size_t)(((ks - 1) * 2 + nh) * 5120) + (l << 2);
#pragma unroll
        for (int mt = 0; mt < 5; ++mt)
#pragma unroll
            for (int nf = 0; nf < 4; ++nf)
                *(floatx4*)&dst[(mt * 4 + nf) * 256] = acc[mt][nf];
    }
    __syncthreads();

    if (ks == 0) {
#pragma unroll
        for (int s = 0; s < 3; ++s) {
            const float* src = red + (size_t)((s * 2 + nh) * 5120) + (l << 2);
#pragma unroll
            for (int mt = 0; mt < 5; ++mt)
#pragma unroll
                for (int nf = 0; nf < 4; ++nf)
                    acc[mt][nf] += *(const floatx4*)&src[(mt * 4 + nf) * 256];
        }
        const int y = h0 + nh;
#pragma unroll
        for (int mt = 0; mt < 5; ++mt) {
#pragma unroll
            for (int rg = 0; rg < 4; ++rg) {
                int oc = mt * 16 + quad * 4 + rg;
                if (oc < COFF) {
                    float bias = b_off[oc];
#pragma unroll
                    for (int nf = 0; nf < 4; ++nf)
                        offs[(((size_t)(b * COFF + oc)) << 12) + (y << 6) + nf * 16 + lane16] =
                            acc[mt][nf][rg] + bias;
                }
            }
        }
    }
}

// ---------------------------------------------------------------------------
// Kernel 2 v4 (NHWC fp16): deformable conv, MFMA f16, 2-ROW blocks.
// PROVEN-BEST configuration (rounds 5/9, 140-141us total). Unchanged.
//  * wa2[2] per-tap A double-buffer with register prefetch, ONE barrier/tap.
//  * XOR-swizzled unpadded gather window (the LDS window is the coalescing
//    device: windowless v6 measured 74.9us, L1 tag-throughput bound).
//  * 48KB window + 16KB wa2 = 64KB => 2 blocks/CU.
// ---------------------------------------------------------------------------
__global__ __launch_bounds__(512) void deform_nhwc(
    const _Float16* __restrict__ xh, const float* __restrict__ offs,
    const _Float16* __restrict__ wT3, const float* __restrict__ b_def,
    float* __restrict__ out)
{
    const int hh = blockIdx.x & 31;
    const int bg = blockIdx.x >> 5;
    const int g  = bg & 3;
    const int b  = bg >> 2;
    const int h0 = hh << 1;
    const int t  = threadIdx.x;
    const int wv = t >> 6;
    const int l  = t & 63;
    const int lane16 = l & 15;
    const int quad   = l >> 4;
    const int p  = (wv & 3) * 16 + lane16;
    const int hw = h0 + (wv >> 2);        // this wave's output row

    // [r 0..5][px 0..63][8 slots of 16B, phys slot = logical ^ (px&7)]
    __shared__ _Float16 ls[6 * 64 * 64];    // 49152 B
    __shared__ _Float16 wa2[2][4096];       // per-tap A dbuf, 2 x 8192 B

    floatx4 acc[4];
#pragma unroll
    for (int mt = 0; mt < 4; ++mt) acc[mt] = (floatx4){0.f, 0.f, 0.f, 0.f};

    // ---- stage 6-row window (rows h0-2..h0+3, group g's 64 channels) ----
#pragma unroll
    for (int it = 0; it < 6; ++it) {
        int id  = it * 512 + t;          // < 3072
        int c16 = id & 7;                // logical slot
        int px  = (id >> 3) & 63;
        int r   = id >> 9;               // 0..5
        int r_img = h0 - 2 + r;
        uint4 v = make_uint4(0, 0, 0, 0);
        if ((unsigned)r_img < 64u)
            v = *(const uint4*)(xh + (((size_t)(b * HW + (r_img << 6) + px)) << 8)
                                   + g * 64 + c16 * 8);
        *(uint4*)&ls[((r * 64 + px) << 6) + ((c16 ^ (px & 7)) << 3)] = v;
    }

    // ---- stage tap-0 A tile (8KB = 512 uint4, 1 per thread) ----
    {
        const uint4* asrc = (const uint4*)(wT3 + ((size_t)(g * 9) << 12));
        uint4 a0 = asrc[t];
        *(uint4*)&wa2[0][t * 8] = a0;
    }

    // prefetch all 18 offset values for this wave's pixel/row
    float dyv[9], dxv[9];
    {
        const float* ofb = offs + (((size_t)(b * COFF + g * 18)) * HH + hw) * WW + p;
#pragma unroll
        for (int k = 0; k < 9; ++k) {
            dyv[k] = ofb[(size_t)(2 * k) * HW];
            dxv[k] = ofb[(size_t)(2 * k + 1) * HW];
        }
    }

    __syncthreads();

    const _Float16* xg = xh + (((size_t)(b * HW)) << 8) + g * 64;

#pragma unroll
    for (int k = 0; k < 9; ++k) {
        // ---- prefetch next tap's A tile into a register ----
        uint4 pw0;
        if (k < 8) {
            const uint4* asrc = (const uint4*)(wT3 + ((size_t)(g * 9 + k + 1) << 12));
            pw0 = asrc[t];
        }

        // ---- bilinear params ----
        float py = dyv[k] + (float)(hw + (k / 3) - 1);
        float px_ = dxv[k] + (float)(p + (k % 3) - 1);
        float y0f = floorf(py), x0f = floorf(px_);
        float fy = py - y0f, fx = px_ - x0f;
        int y0 = (int)y0f, x0 = (int)x0f;
        float wy0 = ((y0 >= 0) & (y0 < HH)) ? (1.f - fy) : 0.f;
        float wy1 = ((y0 >= -1) & (y0 < HH - 1)) ? fy : 0.f;
        float wx0 = ((x0 >= 0) & (x0 < WW)) ? (1.f - fx) : 0.f;
        float wx1 = ((x0 >= -1) & (x0 < WW - 1)) ? fx : 0.f;
        int yia = min(max(y0, 0), HH - 1), yib = min(max(y0 + 1, 0), HH - 1);
        int xia = min(max(x0, 0), WW - 1), xib = min(max(x0 + 1, 0), WW - 1);
        bool inWin = (y0 >= h0 - 2) & (y0 <= h0 + 2);

        int wa_ = min(max(yia - (h0 - 2), 0), 5);
        int wb_ = min(max(yib - (h0 - 2), 0), 5);

        // swizzled gather: phys slot = quad ^ (px&7); high half-frag = ^32
        int soa = (quad ^ (xia & 7)) << 3;
        int sob = (quad ^ (xib & 7)) << 3;
        const _Float16* pa = ls + ((wa_ * 64 + xia) << 6);
        const _Float16* pb = ls + ((wa_ * 64 + xib) << 6);
        const _Float16* pc = ls + ((wb_ * 64 + xia) << 6);
        const _Float16* pd = ls + ((wb_ * 64 + xib) << 6);

        half8 aL = *(const half8*)(pa + soa);
        half8 bL = *(const half8*)(pb + sob);
        half8 cL = *(const half8*)(pc + soa);
        half8 dL = *(const half8*)(pd + sob);
        half8 aH = *(const half8*)(pa + (soa ^ 32));
        half8 bH = *(const half8*)(pb + (sob ^ 32));
        half8 cH = *(const half8*)(pc + (soa ^ 32));
        half8 dH = *(const half8*)(pd + (sob ^ 32));

        if (!inWin) {   // rare: sample escaped the staged window (still exact)
            const int co = quad * 8;
            const _Float16* qa = xg + (((size_t)((yia << 6) + xia)) << 8);
            const _Float16* qb = xg + (((size_t)((yia << 6) + xib)) << 8);
            const _Float16* qc = xg + (((size_t)((yib << 6) + xia)) << 8);
            const _Float16* qd = xg + (((size_t)((yib << 6) + xib)) << 8);
            aL = *(const half8*)(qa + co);  aH = *(const half8*)(qa + co + 32);
            bL = *(const half8*)(qb + co);  bH = *(const half8*)(qb + co + 32);
            cL = *(const half8*)(qc + co);  cH = *(const half8*)(qc + co + 32);
            dL = *(const half8*)(qd + co);  dH = *(const half8*)(qd + co + 32);
        }

        // ---- packed fp16 blend ----
        half8 W00 = splat8(wy0 * wx0), W01 = splat8(wy0 * wx1);
        half8 W10 = splat8(wy1 * wx0), W11 = splat8(wy1 * wx1);
        half8 f0 = aL * W00 + bL * W01 + cL * W10 + dL * W11;
        half8 f1 = aH * W00 + bH * W01 + cH * W10 + dH * W11;

        // ---- A-frags from LDS dbuf + MFMA ----
        const _Float16* wk = &wa2[k & 1][l * 8];
#pragma unroll
        for (int mt = 0; mt < 4; ++mt) {
            half8 a0 = *(const half8*)(wk + (mt * 2 + 0) * 512);
            half8 a1 = *(const half8*)(wk + (mt * 2 + 1) * 512);
            acc[mt] = __builtin_amdgcn_mfma_f32_16x16x32_f16(a0, f0, acc[mt], 0, 0, 0);
            acc[mt] = __builtin_amdgcn_mfma_f32_16x16x32_f16(a1, f1, acc[mt], 0, 0, 0);
        }

        // ---- commit next tap's A tile; single barrier per tap ----
        if (k < 8) {
            *(uint4*)&wa2[(k + 1) & 1][t * 8] = pw0;
            __syncthreads();
        }
    }

#pragma unroll
    for (int mt = 0; mt < 4; ++mt) {
#pragma unroll
        for (int rg = 0; rg < 4; ++rg) {
            int o = mt * 16 + quad * 4 + rg;
            float v = acc[mt][rg] + b_def[g * CG + o];
            out[((size_t)(b * CIN + g * CG + o) * HH + hw) * WW + p] = v;
        }
    }
}

// ===========================================================================
// FALLBACK PATH (ws too small for xh): fp32 correctness-first (not expected
// to be taken -- ws has been >= 26.9MB in all rounds).
// ===========================================================================
__global__ __launch_bounds__(256) void conv_off_fb(
    const float* __restrict__ x, const float* __restrict__ w_off,
    const float* __restrict__ b_off, float* __restrict__ offs)
{
    const int b = blockIdx.x >> 6;
    const int h = blockIdx.x & 63;
    const int t = threadIdx.x;
    const int w = t & 63;
    const int q = t >> 6;

    __shared__ float xsf[3][8][WW + 2];
    __shared__ float wtf[9][8][COFF];

    float acc[18];
#pragma unroll
    for (int j = 0; j < 18; ++j) acc[j] = 0.f;

    for (int c0 = 0; c0 < CIN; c0 += 8) {
        __syncthreads();
        for (int i = t; i < 3 * 8 * (WW + 2); i += 256) {
            int wp = i % (WW + 2);
            int rem = i / (WW + 2);
            int cc = rem % 8;
            int ky = rem / 8;
            int yy = h + ky - 1;
            int xx = wp - 1;
            float v = 0.f;
            if (yy >= 0 && yy < HH && xx >= 0 && xx < WW)
                v = x[(((size_t)b * CIN + c0 + cc) * HH + yy) * WW + xx];
            xsf[ky][cc][wp] = v;
        }
        for (int i = t; i < 9 * 8 * COFF; i += 256) {
            int oc = i % COFF;
            int rem = i / COFF;
            int cc = rem % 8;
            int tap = rem / 8;
            wtf[tap][cc][oc] = w_off[((size_t)oc * CIN + c0 + cc) * 9 + tap];
        }
        __syncthreads();
        for (int tap = 0; tap < 9; ++tap) {
            const int ky = tap / 3, kx = tap % 3;
#pragma unroll
            for (int cc = 0; cc < 8; ++cc) {
                float xv = xsf[ky][cc][w + kx];
#pragma unroll
                for (int j = 0; j < 18; ++j)
                    acc[j] += xv * wtf[tap][cc][q * 18 + j];
            }
        }
    }
#pragma unroll
    for (int j = 0; j < 18; ++j) {
        int oc = q * 18 + j;
        offs[(((size_t)b * COFF + oc) * HH + h) * WW + w] = acc[j] + b_off[oc];
    }
}

__global__ __launch_bounds__(256) void deform_fb(
    const float* __restrict__ x, const float* __restrict__ offs,
    const float* __restrict__ w_def, const float* __restrict__ b_def,
    float* __restrict__ out)
{
    const int h  = blockIdx.x & 63;
    const int bg = blockIdx.x >> 6;
    const int g  = bg & 3;
    const int b  = bg >> 2;
    const int t  = threadIdx.x;
    const int w  = t & 63;
    const int q  = t >> 6;

    __shared__ float vlds[CG][WW];
    __shared__ float wt2[CG][CG];
    __shared__ int   sidx[4][WW];
    __shared__ float swgt[4][WW];

    float acc[16];
#pragma unroll
    for (int j = 0; j < 16; ++j) acc[j] = 0.f;

    const float* xg = x + ((size_t)(b * CIN + g * CG)) * HW;

    for (int k = 0; k < 9; ++k) {
        __syncthreads();
        if (t < 64) {
            const int ky = k / 3 - 1, kx = k % 3 - 1;
            size_t obase = (((size_t)b * COFF + g * 18 + k * 2) * HH + h) * WW + w;
            float dy = offs[obase];
            float dx = offs[obase + (size_t)HW];
            float py = dy + (float)(h + ky);
            float px = dx + (float)(w + kx);
            float y0 = floorf(py), x0 = floorf(px);
            float fy = py - y0, fx = px - x0;
#pragma unroll
            for (int cn = 0; cn < 4; ++cn) {
                float yy = y0 + (float)(cn >> 1);
                float xx = x0 + (float)(cn & 1);
                float wy = (cn >> 1) ? fy : (1.f - fy);
                float wx = (cn & 1) ? fx : (1.f - fx);
                bool valid = (yy >= 0.f) && (yy < (float)HH) &&
                             (xx >= 0.f) && (xx < (float)WW);
                int yi = (int)fminf(fmaxf(yy, 0.f), (float)(HH - 1));
                int xi = (int)fminf(fmaxf(xx, 0.f), (float)(WW - 1));
                sidx[cn][w] = yi * WW + xi;
                swgt[cn][w] = valid ? (wy * wx) : 0.f;
            }
        }
        for (int i = t; i < CG * CG; i += 256) {
            int o = i >> 6, c = i & 63;
            wt2[c][o] = w_def[((size_t)(g * CG + o) * CG + c) * 9 + k];
        }
        __syncthreads();

        int   i0 = sidx[0][w], i1 = sidx[1][w], i2 = sidx[2][w], i3 = sidx[3][w];
        float g0 = swgt[0][w], g1 = swgt[1][w], g2 = swgt[2][w], g3 = swgt[3][w];
#pragma unroll
        for (int j = 0; j < 16; ++j) {
            int c = q * 16 + j;
            const float* xc = xg + (size_t)c * HW;
            float v = g0 * xc[i0] + g1 * xc[i1] + g2 * xc[i2] + g3 * xc[i3];
            vlds[c][w] = v;
        }
        __syncthreads();

#pragma unroll 4
        for (int c = 0; c < CG; ++c) {
            float xv = vlds[c][w];
#pragma unroll
            for (int j = 0; j < 16; ++j)
                acc[j] += xv * wt2[c][q * 16 + j];
        }
    }

#pragma unroll
    for (int j = 0; j < 16; ++j) {
        int o = q * 16 + j;
        out[(((size_t)b * CIN + g * CG + o) * HH + h) * WW + w] =
            acc[j] + b_def[g * CG + o];
    }
}

extern "C" void kernel_launch(void* const* d_in, const int* in_sizes, int n_in,
                              void* d_out, int out_size, void* d_ws, size_t ws_size,
                              hipStream_t stream) {
    const float* x     = (const float*)d_in[0];
    const float* w_off = (const float*)d_in[1];
    const float* b_off = (const float*)d_in[2];
    const float* w_def = (const float*)d_in[3];
    const float* b_def = (const float*)d_in[4];
    float* out = (float*)d_out;

    char* ws = (char*)d_ws;
    float*     offs = (float*)ws;
    _Float16*  wT3  = (_Float16*)(ws + (size_t)OFFS_ELEMS * 4);
    _Float16*  woT3 = (_Float16*)(ws + (size_t)OFFS_ELEMS * 4 + (size_t)WT_ELEMS * 2);
    _Float16*  xh   = (_Float16*)(ws + XH_BYTE_OFF);

    if (ws_size >= NEED_NHWC) {
        prep_kernel<<<512 + PREPW_BLOCKS, 256, 0, stream>>>(x, w_def, w_off, xh, wT3, woT3);
        conv_off_nhwc<<<BATCH * 32, 512, 0, stream>>>(xh, woT3, b_off, offs);
        deform_nhwc<<<BATCH * OG * 32, 512, 0, stream>>>(xh, offs, wT3, b_def, out);
    } else {
        conv_off_fb<<<BATCH * HH, 256, 0, stream>>>(x, w_off, b_off, offs);
        deform_fb<<<BATCH * OG * HH, 256, 0, stream>>>(x, offs, w_def, b_def, out);
    }
}